// Round 1
// baseline (95.579 us; speedup 1.0000x reference)
//
#include <hip/hip_runtime.h>

// TemporalJitter: out[b,pos,:] = x[b, src(b,pos), :] where
// src(b,pos) = max{ t : t + shifts[b,t] == pos, 0<=t<T }, else zeros.
// Since |shift| <= 2, candidates are t in [pos-2, pos+2] — scan high->low.
//
// B=64, T=128, N=8192 (fp32). Memory-bound row-copy: ~512 MB total traffic.

#define B_DIM 64
#define T_DIM 128
#define N_DIM 8192
#define N4    (N_DIM / 4)   // 2048 float4 per row
#define MAX_SHIFT 2

__global__ __launch_bounds__(256) void temporal_jitter_kernel(
    const float4* __restrict__ x,
    const int*    __restrict__ shifts,
    float4*       __restrict__ out)
{
    const int row = blockIdx.x;          // row = b*T + pos
    const int b   = row >> 7;            // / T_DIM
    const int pos = row & (T_DIM - 1);

    // Find the source timestep: largest t in [pos-2, pos+2] with t+shift==pos.
    int src = -1;
    const int lo = pos - MAX_SHIFT < 0 ? 0 : pos - MAX_SHIFT;
    const int hi = pos + MAX_SHIFT > T_DIM - 1 ? T_DIM - 1 : pos + MAX_SHIFT;
    #pragma unroll
    for (int t = hi; t >= lo; --t) {
        if (shifts[b * T_DIM + t] == pos - t) { src = t; break; }
    }

    float4* __restrict__ dst = out + (size_t)row * N4;

    if (src >= 0) {
        const float4* __restrict__ srow = x + ((size_t)b * T_DIM + src) * N4;
        #pragma unroll
        for (int i = threadIdx.x; i < N4; i += 256) {
            dst[i] = srow[i];
        }
    } else {
        const float4 z = make_float4(0.f, 0.f, 0.f, 0.f);
        #pragma unroll
        for (int i = threadIdx.x; i < N4; i += 256) {
            dst[i] = z;
        }
    }
}

extern "C" void kernel_launch(void* const* d_in, const int* in_sizes, int n_in,
                              void* d_out, int out_size, void* d_ws, size_t ws_size,
                              hipStream_t stream)
{
    const float4* x      = (const float4*)d_in[0];
    const int*    shifts = (const int*)d_in[1];
    float4*       out    = (float4*)d_out;

    dim3 grid(B_DIM * T_DIM);   // 8192 blocks, one per output row
    dim3 block(256);
    temporal_jitter_kernel<<<grid, block, 0, stream>>>(x, shifts, out);
}

// Round 2
// 87.635 us; speedup vs baseline: 1.0906x; 1.0906x over previous
//
#include <hip/hip_runtime.h>

// TemporalJitter: out[b,pos,:] = x[b, src(b,pos), :] where
// src(b,pos) = max{ t : t + shifts[b,t] == pos, 0<=t<T }, else zeros.
// |shift| <= 2, so candidates are t in [pos-2, pos+2] — scan high->low.
//
// B=64, T=128, N=8192 (fp32). Pure streaming: each x row is consumed by at
// most ONE output row (one shift per t -> unique target), so there is zero
// reuse. Non-temporal loads/stores bypass L2/L3 write-allocate churn.

#define B_DIM 64
#define T_DIM 128
#define N_DIM 8192
#define N4    (N_DIM / 4)   // 2048 float4 per row
#define MAX_SHIFT 2

typedef float f4 __attribute__((ext_vector_type(4)));

__global__ __launch_bounds__(256) void temporal_jitter_kernel(
    const f4* __restrict__ x,
    const int* __restrict__ shifts,
    f4* __restrict__ out)
{
    const int row = blockIdx.x;          // row = b*T + pos
    const int b   = row >> 7;            // / T_DIM
    const int pos = row & (T_DIM - 1);

    // Find the source timestep: largest t in [pos-2, pos+2] with t+shift==pos.
    int src = -1;
    const int lo = pos - MAX_SHIFT < 0 ? 0 : pos - MAX_SHIFT;
    const int hi = pos + MAX_SHIFT > T_DIM - 1 ? T_DIM - 1 : pos + MAX_SHIFT;
    #pragma unroll
    for (int t = hi; t >= lo; --t) {
        if (shifts[b * T_DIM + t] == pos - t) { src = t; break; }
    }

    f4* __restrict__ dst = out + (size_t)row * N4;

    if (src >= 0) {
        const f4* __restrict__ srow = x + ((size_t)b * T_DIM + src) * N4;
        #pragma unroll
        for (int i = threadIdx.x; i < N4; i += 256) {
            f4 v = __builtin_nontemporal_load(&srow[i]);
            __builtin_nontemporal_store(v, &dst[i]);
        }
    } else {
        const f4 z = {0.f, 0.f, 0.f, 0.f};
        #pragma unroll
        for (int i = threadIdx.x; i < N4; i += 256) {
            __builtin_nontemporal_store(z, &dst[i]);
        }
    }
}

extern "C" void kernel_launch(void* const* d_in, const int* in_sizes, int n_in,
                              void* d_out, int out_size, void* d_ws, size_t ws_size,
                              hipStream_t stream)
{
    const f4*  x      = (const f4*)d_in[0];
    const int* shifts = (const int*)d_in[1];
    f4*        out    = (f4*)d_out;

    dim3 grid(B_DIM * T_DIM);   // 8192 blocks, one per output row
    dim3 block(256);
    temporal_jitter_kernel<<<grid, block, 0, stream>>>(x, shifts, out);
}